// Round 2
// 369.288 us; speedup vs baseline: 1.0590x; 1.0590x over previous
//
#include <hip/hip_runtime.h>
#include <math.h>

#define EMB   4096
#define DIM   4096
#define TPREV 8192

// ws layout (floats):
//   [0,4096)        q
//   [4096,8192)     k
//   [8192,12288)    v
//   [12288,20481)   scores / a   (8193)
//   [20544, ...)    score partials: part[chunk][t], 128 x 8192 floats (4 MB)
#define WS_Q    0
#define WS_K    DIM
#define WS_V    (2*DIM)
#define WS_A    (3*DIM)
#define WS_PART 20544

typedef float f4 __attribute__((ext_vector_type(4)));

__device__ __forceinline__ f4 ntl(const f4* p) {
    return __builtin_nontemporal_load(p);
}
__device__ __forceinline__ float dotf4(f4 a, f4 b) {
    return a.x * b.x + a.y * b.y + a.z * b.z + a.w * b.w;
}

// ---------------------------------------------------------------------------
// K1: q,k,v GEMVs. Persistent: 2048 blocks x 256, each block 6 rows.
// x fragment (16 floats/thread) register-resident, loaded once per block.
// W rows streamed with non-temporal float4 loads (read-once data).
__global__ __launch_bounds__(256) void qkv_kernel(
    const float* __restrict__ x,
    const float* __restrict__ Wq, const float* __restrict__ Wk,
    const float* __restrict__ Wv, float* __restrict__ ws) {
    const int tid = threadIdx.x;
    const f4* xv = (const f4*)x;
    // x is 16 KB, L2-hot after first touch; keep this thread's cols in regs
    f4 x0 = xv[tid];
    f4 x1 = xv[tid + 256];
    f4 x2 = xv[tid + 512];
    f4 x3 = xv[tid + 768];

    __shared__ float red[4];
    for (int it = 0; it < 6; ++it) {
        const int wid = blockIdx.x + 2048 * it;   // 0..12287
        const int m = wid >> 12;                  // matrix (uniform per block)
        const int r = wid & 4095;                 // row
        const float* W = (m == 0) ? Wq : (m == 1) ? Wk : Wv;
        const f4* row = (const f4*)(W + (size_t)r * EMB);

        f4 w0 = ntl(row + tid);
        f4 w1 = ntl(row + tid + 256);
        f4 w2 = ntl(row + tid + 512);
        f4 w3 = ntl(row + tid + 768);
        float s = dotf4(w0, x0) + dotf4(w1, x1) + dotf4(w2, x2) + dotf4(w3, x3);

#pragma unroll
        for (int off = 32; off > 0; off >>= 1) s += __shfl_down(s, off, 64);
        if ((tid & 63) == 0) red[tid >> 6] = s;
        __syncthreads();
        if (tid == 0) ws[WS_Q + m * DIM + r] = red[0] + red[1] + red[2] + red[3];
        __syncthreads();
    }
}

// ---------------------------------------------------------------------------
// K2: score partials. grid (8, 128) = 1024 blocks.
// blockIdx.x = t-tile (1024 wide), blockIdx.y = d-chunk (32 rows).
// 8 independent non-temporal row loads in flight before each FMA batch.
__global__ __launch_bounds__(256) void score_kernel(
    const float* __restrict__ Kc, float* __restrict__ ws) {
    __shared__ float qs[32];
    const int d0 = blockIdx.y * 32;
    if (threadIdx.x < 32) qs[threadIdx.x] = ws[WS_Q + d0 + threadIdx.x];
    __syncthreads();

    const size_t t = (size_t)blockIdx.x * 1024 + (size_t)threadIdx.x * 4;
    const float* base = Kc + (size_t)d0 * TPREV + t;

    f4 acc = {0.f, 0.f, 0.f, 0.f};
#pragma unroll
    for (int g = 0; g < 4; ++g) {     // 4 batches of 8 rows
        f4 k0 = ntl((const f4*)(base + (size_t)(8 * g + 0) * TPREV));
        f4 k1 = ntl((const f4*)(base + (size_t)(8 * g + 1) * TPREV));
        f4 k2 = ntl((const f4*)(base + (size_t)(8 * g + 2) * TPREV));
        f4 k3 = ntl((const f4*)(base + (size_t)(8 * g + 3) * TPREV));
        f4 k4 = ntl((const f4*)(base + (size_t)(8 * g + 4) * TPREV));
        f4 k5 = ntl((const f4*)(base + (size_t)(8 * g + 5) * TPREV));
        f4 k6 = ntl((const f4*)(base + (size_t)(8 * g + 6) * TPREV));
        f4 k7 = ntl((const f4*)(base + (size_t)(8 * g + 7) * TPREV));
        acc += qs[8 * g + 0] * k0 + qs[8 * g + 1] * k1
             + qs[8 * g + 2] * k2 + qs[8 * g + 3] * k3
             + qs[8 * g + 4] * k4 + qs[8 * g + 5] * k5
             + qs[8 * g + 6] * k6 + qs[8 * g + 7] * k7;
    }
    *(f4*)(ws + WS_PART + (size_t)blockIdx.y * TPREV + t) = acc;
}

// ---------------------------------------------------------------------------
// K3: reduce 128 chunks + sigmoid. grid 65 blocks. (unchanged, proven)
__global__ __launch_bounds__(256) void reduce_sigmoid_kernel(
    float* __restrict__ ws) {
    if (blockIdx.x < 64) {
        const float4* p = (const float4*)(ws + WS_PART);
        int f4i   = threadIdx.x & 31;
        int slice = threadIdx.x >> 5;
        size_t idx = (size_t)(slice * 16) * (TPREV / 4) + (size_t)blockIdx.x * 32 + f4i;

        float4 s = {0.f, 0.f, 0.f, 0.f};
#pragma unroll 4
        for (int c = 0; c < 16; ++c) {
            float4 v = p[idx + (size_t)c * (TPREV / 4)];
            s.x += v.x; s.y += v.y; s.z += v.z; s.w += v.w;
        }
        __shared__ float4 red[256];
        red[threadIdx.x] = s;
        __syncthreads();
        if (threadIdx.x < 32) {
            float4 tot = red[threadIdx.x];
#pragma unroll
            for (int sl = 1; sl < 8; ++sl) {
                float4 v = red[sl * 32 + threadIdx.x];
                tot.x += v.x; tot.y += v.y; tot.z += v.z; tot.w += v.w;
            }
            tot.x = 1.0f / (1.0f + __expf(-tot.x * 0.015625f));
            tot.y = 1.0f / (1.0f + __expf(-tot.y * 0.015625f));
            tot.z = 1.0f / (1.0f + __expf(-tot.z * 0.015625f));
            tot.w = 1.0f / (1.0f + __expf(-tot.w * 0.015625f));
            ((float4*)(ws + WS_A))[(size_t)blockIdx.x * 32 + threadIdx.x] = tot;
        }
    } else {
        const float* q = ws + WS_Q;
        const float* k = ws + WS_K;
        float s = 0.0f;
        int base = threadIdx.x * 16;
#pragma unroll 16
        for (int i = 0; i < 16; ++i) s += q[base + i] * k[base + i];
        __shared__ float red[256];
        red[threadIdx.x] = s;
        __syncthreads();
        for (int off = 128; off > 0; off >>= 1) {
            if (threadIdx.x < off) red[threadIdx.x] += red[threadIdx.x + off];
            __syncthreads();
        }
        if (threadIdx.x == 0) {
            float v = red[0] * 0.015625f;
            ws[WS_A + TPREV] = 1.0f / (1.0f + __expf(-v));
        }
    }
}

// ---------------------------------------------------------------------------
// K4: z[d] = dot(V_cache[d,:], a) + v[d]*a[8192].
// Persistent: 1024 blocks x 256, each block 4 rows.
// a fragment (32 floats/thread) register-resident, loaded once per block.
// V rows streamed with non-temporal float4 loads.
__global__ __launch_bounds__(256) void out_kernel(
    const float* __restrict__ Vc, const float* __restrict__ ws,
    float* __restrict__ out) {
    const int tid = threadIdx.x;
    const f4* av = (const f4*)(ws + WS_A);
    f4 a0 = av[tid];
    f4 a1 = av[tid + 256];
    f4 a2 = av[tid + 512];
    f4 a3 = av[tid + 768];
    f4 a4 = av[tid + 1024];
    f4 a5 = av[tid + 1280];
    f4 a6 = av[tid + 1536];
    f4 a7 = av[tid + 1792];
    const float atail = ws[WS_A + TPREV];

    __shared__ float red[4];
    for (int it = 0; it < 4; ++it) {
        const int d = blockIdx.x + 1024 * it;     // 0..4095
        const f4* row = (const f4*)(Vc + (size_t)d * TPREV);

        f4 v0 = ntl(row + tid);
        f4 v1 = ntl(row + tid + 256);
        f4 v2 = ntl(row + tid + 512);
        f4 v3 = ntl(row + tid + 768);
        f4 v4 = ntl(row + tid + 1024);
        f4 v5 = ntl(row + tid + 1280);
        f4 v6 = ntl(row + tid + 1536);
        f4 v7 = ntl(row + tid + 1792);
        float s = dotf4(v0, a0) + dotf4(v1, a1) + dotf4(v2, a2) + dotf4(v3, a3)
                + dotf4(v4, a4) + dotf4(v5, a5) + dotf4(v6, a6) + dotf4(v7, a7);

#pragma unroll
        for (int off = 32; off > 0; off >>= 1) s += __shfl_down(s, off, 64);
        if ((tid & 63) == 0) red[tid >> 6] = s;
        __syncthreads();
        if (tid == 0)
            out[d] = red[0] + red[1] + red[2] + red[3]
                   + ws[WS_V + d] * atail;
        __syncthreads();
    }
}

// ---------------------------------------------------------------------------
extern "C" void kernel_launch(void* const* d_in, const int* in_sizes, int n_in,
                              void* d_out, int out_size, void* d_ws, size_t ws_size,
                              hipStream_t stream) {
    (void)in_sizes; (void)n_in; (void)out_size; (void)ws_size;
    const float* x  = (const float*)d_in[0];
    const float* Wq = (const float*)d_in[1];
    const float* Wk = (const float*)d_in[2];
    const float* Wv = (const float*)d_in[3];
    const float* Kc = (const float*)d_in[4];
    const float* Vc = (const float*)d_in[5];
    float* out = (float*)d_out;
    float* ws  = (float*)d_ws;

    qkv_kernel<<<2048, 256, 0, stream>>>(x, Wq, Wk, Wv, ws);
    score_kernel<<<dim3(8, 128), 256, 0, stream>>>(Kc, ws);
    reduce_sigmoid_kernel<<<65, 256, 0, stream>>>(ws);
    out_kernel<<<1024, 256, 0, stream>>>(Vc, ws, out);
}